// Round 6
// baseline (201.638 us; speedup 1.0000x reference)
//
#include <hip/hip_runtime.h>
#include <stdint.h>

typedef __attribute__((ext_vector_type(8))) __bf16 bf16x8;
typedef __attribute__((ext_vector_type(4))) float f32x4;
typedef __attribute__((ext_vector_type(16))) float f32x16;
typedef __attribute__((ext_vector_type(4))) unsigned u32x4;

#define SEQ 2048
#define DMODEL 1024
#define NHEAD 16
#define HDIM 64
#define BTOK 4096   // B*S
#define NQKV 3072   // stacked q,k,v output cols

// ---- async global->LDS, 16B per lane; LDS dest must be wave-linear ----
__device__ __forceinline__ void gload_lds16(const __bf16* g, __bf16* l) {
  __builtin_amdgcn_global_load_lds(
      (__attribute__((address_space(1))) void*)const_cast<__bf16*>(g),
      (__attribute__((address_space(3))) void*)l, 16, 0, 0);
}

__device__ __forceinline__ f32x4 mfma16(bf16x8 a, bf16x8 b, f32x4 c) {
  return __builtin_amdgcn_mfma_f32_16x16x32_bf16(a, b, c, 0, 0, 0);
}
__device__ __forceinline__ f32x16 mfma32(bf16x8 a, bf16x8 b, f32x16 c) {
  return __builtin_amdgcn_mfma_f32_32x32x16_bf16(a, b, c, 0, 0, 0);
}

// pack 2 f32 -> 1 u32 of 2 bf16 (lo in low half)
__device__ __forceinline__ unsigned cvtpk(float lo, float hi) {
  unsigned r;
  asm("v_cvt_pk_bf16_f32 %0, %1, %2" : "=v"(r) : "v"(lo), "v"(hi));
  return r;
}
// swap a's lanes 32-63 with b's lanes 0-31 (in place)
__device__ __forceinline__ void plswap(unsigned& a, unsigned& b) {
  asm volatile("v_permlane32_swap_b32 %0, %1" : "+v"(a), "+v"(b));
}

// swizzled 16B-fragment pointer into a tile with 128B rows (64 bf16/row).
__device__ __forceinline__ const bf16x8* frag128(const __bf16* tile, int row, int c16) {
  return reinterpret_cast<const bf16x8*>(tile) + ((row << 3) + (c16 ^ (row & 7)));
}

// ---------------- fp32 -> bf16 convert, 8 elems/thread ----------------
__global__ __launch_bounds__(256) void cvt_f32_bf16(const float* __restrict__ in,
                                                    __bf16* __restrict__ out, int n8) {
  int i = blockIdx.x * 256 + threadIdx.x;
  if (i >= n8) return;
  const float4* p = reinterpret_cast<const float4*>(in) + (size_t)i * 2;
  float4 a = p[0], b = p[1];
  bf16x8 o;
  o[0] = (__bf16)a.x; o[1] = (__bf16)a.y; o[2] = (__bf16)a.z; o[3] = (__bf16)a.w;
  o[4] = (__bf16)b.x; o[5] = (__bf16)b.y; o[6] = (__bf16)b.z; o[7] = (__bf16)b.w;
  reinterpret_cast<bf16x8*>(out)[i] = o;
}

// ---- 4 weight matrices (Wq,Wk,Wv,Wo) -> contiguous bf16 in one launch ----
__global__ __launch_bounds__(256) void cvt4_f32_bf16(const float* __restrict__ w0,
                                                     const float* __restrict__ w1,
                                                     const float* __restrict__ w2,
                                                     const float* __restrict__ w3,
                                                     __bf16* __restrict__ out, int n8per) {
  const int y = blockIdx.y;
  const float* src = (y == 0) ? w0 : (y == 1) ? w1 : (y == 2) ? w2 : w3;
  int i = blockIdx.x * 256 + threadIdx.x;
  if (i >= n8per) return;
  const float4* p = reinterpret_cast<const float4*>(src) + (size_t)i * 2;
  float4 a = p[0], b = p[1];
  bf16x8 o;
  o[0] = (__bf16)a.x; o[1] = (__bf16)a.y; o[2] = (__bf16)a.z; o[3] = (__bf16)a.w;
  o[4] = (__bf16)b.x; o[5] = (__bf16)b.y; o[6] = (__bf16)b.z; o[7] = (__bf16)b.w;
  reinterpret_cast<bf16x8*>(out)[(size_t)y * n8per + i] = o;
}

// ------ C = A(4096xK) * Bw(NxK)^T + bias, 2-phase prefetch dbuf ------
template <int MODE>
__global__ __launch_bounds__(256) void gemm_bt(
    const __bf16* __restrict__ A, const __bf16* __restrict__ Bw,
    const float* __restrict__ bias0, const float* __restrict__ bias1,
    const float* __restrict__ bias2,
    __bf16* __restrict__ qo, __bf16* __restrict__ ko, __bf16* __restrict__ vo,
    float* __restrict__ outf) {
  constexpr int K = DMODEL;
  __shared__ __bf16 Alds[2][128][32];
  __shared__ __bf16 Blds[2][128][32];
  const int t = threadIdx.x;
  const int lane = t & 63;
  const int wr = (t >> 6) >> 1, wc = (t >> 6) & 1;
  const int bm0 = blockIdx.x * 128, bn0 = blockIdx.y * 128;

  auto stageg = [&](int k0, int buf) {
#pragma unroll
    for (int i = 0; i < 2; ++i) {
      int c = t + i * 256;               // 512 x 16B chunks per tile
      int row = c >> 2, kof = (c & 3) << 3;
      gload_lds16(A + (size_t)(bm0 + row) * K + k0 + kof, &Alds[buf][0][0] + c * 8);
      gload_lds16(Bw + (size_t)(bn0 + row) * K + k0 + kof, &Blds[buf][0][0] + c * 8);
    }
  };

  f32x4 acc[4][4] = {};
  stageg(0, 0);
  __syncthreads();
  int cur = 0;
  for (int k0 = 0; k0 < K; k0 += 32) {
    if (k0 + 32 < K) stageg(k0 + 32, cur ^ 1);  // prefetch hides under compute
    bf16x8 af[4], bfr[4];
#pragma unroll
    for (int m = 0; m < 4; ++m)
      af[m] = *(const bf16x8*)&Alds[cur][wr * 64 + m * 16 + (lane & 15)][(lane >> 4) * 8];
#pragma unroll
    for (int n = 0; n < 4; ++n)
      bfr[n] = *(const bf16x8*)&Blds[cur][wc * 64 + n * 16 + (lane & 15)][(lane >> 4) * 8];
    __builtin_amdgcn_s_setprio(1);
#pragma unroll
    for (int m = 0; m < 4; ++m)
#pragma unroll
      for (int n = 0; n < 4; ++n)
        acc[m][n] = mfma16(af[m], bfr[n], acc[m][n]);
    __builtin_amdgcn_s_setprio(0);
    __syncthreads();  // drains prefetch vmcnt + protects buffer reuse
    cur ^= 1;
  }

  const int r0 = bm0 + wr * 64, c0 = bn0 + wc * 64;
#pragma unroll
  for (int m = 0; m < 4; ++m) {
#pragma unroll
    for (int n = 0; n < 4; ++n) {
#pragma unroll
      for (int r = 0; r < 4; ++r) {
        int gm = r0 + m * 16 + (lane >> 4) * 4 + r;  // token
        int gn = c0 + n * 16 + (lane & 15);          // output col
        float v = acc[m][n][r];
        if (MODE == 0) {
          int which = gn >> 10, j = gn & 1023;
          int h = j >> 6, d = j & 63;
          int b = gm >> 11, s = gm & 2047;
          size_t off = ((size_t)(b * NHEAD + h) * SEQ + s) * HDIM + d;
          if (which == 0)
            qo[off] = (__bf16)(v + bias0[j]);
          else if (which == 1)
            ko[off] = (__bf16)(v + bias1[j]);
          else
            vo[off] = (__bf16)(v + bias2[j]);
        } else {
          outf[(size_t)gm * DMODEL + gn] = v + bias0[gn];
        }
      }
    }
  }
}

// ------- v (BH,S,Hd) -> vt (BH,Hd,S), LDS-tiled 64x64 transpose -------
__global__ __launch_bounds__(256) void transpose_v(const __bf16* __restrict__ v,
                                                   __bf16* __restrict__ vt) {
  __shared__ __bf16 T[64][80];
  const int s0 = blockIdx.x * 64;
  const int bh = blockIdx.y;
  const int t = threadIdx.x;
  const __bf16* src = v + ((size_t)bh * SEQ + s0) * HDIM;
#pragma unroll
  for (int p = 0; p < 2; ++p) {
    int c = t + p * 256;
    int r = c >> 3, d0 = (c & 7) << 3;
    *(bf16x8*)&T[r][d0] = *(const bf16x8*)(src + (size_t)r * HDIM + d0);
  }
  __syncthreads();
#pragma unroll
  for (int p = 0; p < 2; ++p) {
    int c = t + p * 256;
    int d = c & 63, sc = (c >> 6) << 3;
    bf16x8 o;
#pragma unroll
    for (int j = 0; j < 8; ++j) o[j] = T[sc + j][d];
    *(bf16x8*)(vt + ((size_t)bh * HDIM + d) * SEQ + s0 + sc) = o;
  }
}

// --------- flash attention: 8 waves x 32 q = QBLK 256, KVBLK 64 ---------
// grid: (x = B*H -> XCD pin, y = 8 q-tiles of 256 rows). K/V staged once per
// block per tile (1 gload_lds per thread per tensor), shared by all 8 waves.
__global__ __launch_bounds__(512) void attn_fwd(const __bf16* __restrict__ qg,
                                                const __bf16* __restrict__ kg,
                                                const __bf16* __restrict__ vtg,
                                                __bf16* __restrict__ att) {
  __shared__ __align__(16) char smem[36864];  // loop: K[2]8K|V[2]8K=32K; epi: 8x32x72 bf16
  const int t = threadIdx.x, lane = t & 63, w = t >> 6, hi = lane >> 5;
  const int bh = blockIdx.x, qt = blockIdx.y;
  const int q0w = qt * 256 + w * 32;
  const int qabs = q0w + (lane & 31);
  const int kt0 = qt * 4;          // block's first key-tile
  const int ktw = q0w >> 6;        // this wave's first (partially) unmasked tile
  constexpr int NT = SEQ / 64;

  const __bf16* kbase = kg + (size_t)bh * SEQ * HDIM;
  const __bf16* vbase = vtg + (size_t)bh * HDIM * SEQ;

  // Q straight to registers, B-operand layout: col q = lane&31, rows d
  bf16x8 qf[4];
  {
    const __bf16* qptr = qg + ((size_t)bh * SEQ + qabs) * HDIM + hi * 8;
#pragma unroll
    for (int ds = 0; ds < 4; ++ds) qf[ds] = *(const bf16x8*)(qptr + ds * 16);
  }

  // one K chunk + one V chunk per thread per tile (512 x 16B = 8KB each)
  auto stage = [&](int kt_, int buf) {
    int row = t >> 3, sc = (t & 7) ^ (row & 7);
    gload_lds16(kbase + ((size_t)kt_ * 64 + row) * HDIM + sc * 8,
                (__bf16*)(smem + buf * 8192) + t * 8);
    gload_lds16(vbase + (size_t)row * SEQ + kt_ * 64 + sc * 8,
                (__bf16*)(smem + 16384 + buf * 8192) + t * 8);
  };

  f32x16 acc0 = {}, acc1 = {};
  float m = -3.0e38f, l = 0.f;
  const float kScale = 0.03125f;  // 1/sqrt(1024)

  stage(kt0, 0);
  __syncthreads();
  int cur = 0;

  for (int kt = kt0; kt < NT; ++kt) {
    if (kt + 1 < NT) stage(kt + 1, cur ^ 1);  // prefetch under this tile's compute
    if (kt >= ktw) {
      const __bf16* Kt = (const __bf16*)(smem + cur * 8192);
      const __bf16* Vw = (const __bf16*)(smem + 16384 + cur * 8192);

      // S^T[key][q] = K · Q^T : two 32-key halves
      f32x16 s0 = {}, s1 = {};
      __builtin_amdgcn_s_setprio(1);
#pragma unroll
      for (int ds = 0; ds < 4; ++ds) {
        s0 = mfma32(*frag128(Kt, lane & 31, 2 * ds + hi), qf[ds], s0);
        s1 = mfma32(*frag128(Kt, 32 + (lane & 31), 2 * ds + hi), qf[ds], s1);
      }
      __builtin_amdgcn_s_setprio(0);

      // causal mask (keep key >= q): only this wave's diagonal tile is partial
      if (kt == ktw) {
#pragma unroll
        for (int r = 0; r < 16; ++r) {
          int krow = (r & 3) + 8 * (r >> 2) + 4 * hi;
          if (kt * 64 + krow < qabs) s0[r] = -3.0e38f;
          if (kt * 64 + 32 + krow < qabs) s1[r] = -3.0e38f;
        }
      }

      // max: depth-5 tree + one cross-half swap
      float mt[8];
#pragma unroll
      for (int r = 0; r < 8; ++r)
        mt[r] = fmaxf(fmaxf(s0[r], s0[r + 8]), fmaxf(s1[r], s1[r + 8]));
#pragma unroll
      for (int r = 0; r < 4; ++r) mt[r] = fmaxf(mt[r], mt[r + 4]);
      float pmax = fmaxf(fmaxf(mt[0], mt[2]), fmaxf(mt[1], mt[3]));
      pmax = fmaxf(pmax, __shfl_xor(pmax, 32));

      // T13 defer-max, wave-uniform: rescale only if max grew > 256 raw (= e^8)
      if (!__all(pmax - m <= 256.0f)) {
        float newm = fmaxf(m, pmax);
        float corr = __expf((m - newm) * kScale);
        m = newm;
        l *= corr;
#pragma unroll
        for (int r = 0; r < 16; ++r) { acc0[r] *= corr; acc1[r] *= corr; }
      }
      const float bias = m * kScale;
#pragma unroll
      for (int r = 0; r < 16; ++r) s0[r] = __expf(fmaf(s0[r], kScale, -bias));
#pragma unroll
      for (int r = 0; r < 16; ++r) s1[r] = __expf(fmaf(s1[r], kScale, -bias));
      // sum: depth-5 tree (float add not reassociable -> hand-tree)
      float ut[8];
#pragma unroll
      for (int r = 0; r < 8; ++r) ut[r] = (s0[r] + s0[r + 8]) + (s1[r] + s1[r + 8]);
#pragma unroll
      for (int r = 0; r < 4; ++r) ut[r] += ut[r + 4];
      float sum = (ut[0] + ut[2]) + (ut[1] + ut[3]);
      sum += __shfl_xor(sum, 32);
      l += sum;

      // repack P (C-layout f32) -> B-operand bf16 frags: cvt_pk + permlane32_swap
      bf16x8 pb[2][2];
#pragma unroll
      for (int h = 0; h < 2; ++h) {
#pragma unroll
        for (int ks = 0; ks < 2; ++ks) {
          int o = ks * 8;
          unsigned a, b, c, d;
          if (h == 0) {
            a = cvtpk(s0[o + 0], s0[o + 1]); b = cvtpk(s0[o + 4], s0[o + 5]);
            c = cvtpk(s0[o + 2], s0[o + 3]); d = cvtpk(s0[o + 6], s0[o + 7]);
          } else {
            a = cvtpk(s1[o + 0], s1[o + 1]); b = cvtpk(s1[o + 4], s1[o + 5]);
            c = cvtpk(s1[o + 2], s1[o + 3]); d = cvtpk(s1[o + 6], s1[o + 7]);
          }
          plswap(a, b);
          plswap(c, d);
          union { u32x4 u; bf16x8 v; } f;
          f.u[0] = a; f.u[1] = c; f.u[2] = b; f.u[3] = d;
          pb[h][ks] = f.v;
        }
      }

      // O^T[d][q] += V^T · P^T
      __builtin_amdgcn_s_setprio(1);
#pragma unroll
      for (int h = 0; h < 2; ++h)
#pragma unroll
        for (int ks = 0; ks < 2; ++ks) {
          int cc = h * 4 + ks * 2 + hi;
          acc0 = mfma32(*frag128(Vw, lane & 31, cc), pb[h][ks], acc0);
          acc1 = mfma32(*frag128(Vw, 32 + (lane & 31), cc), pb[h][ks], acc1);
        }
      __builtin_amdgcn_s_setprio(0);
    }
    __syncthreads();  // drains prefetch, protects buffer swap
    cur ^= 1;
  }

  // epilogue: O^T -> per-wave bf16 LDS [32][72] -> coalesced 16B stores.
  // Safe overlay: all waves passed the final barrier; each wave touches only
  // its own region.
  float inv = 1.0f / l;
  __bf16* Ob = (__bf16*)smem + (size_t)w * (32 * 72);
#pragma unroll
  for (int r = 0; r < 16; ++r) {
    int d = (r & 3) + 8 * (r >> 2) + 4 * hi;
    Ob[(lane & 31) * 72 + d] = (__bf16)(acc0[r] * inv);
    Ob[(lane & 31) * 72 + 32 + d] = (__bf16)(acc1[r] * inv);
  }
  const int b = bh >> 4, hd = bh & 15;
#pragma unroll
  for (int j = 0; j < 4; ++j) {
    int f = j * 64 + lane;
    int q = f >> 3, c8 = f & 7;
    bf16x8 o = *(const bf16x8*)(Ob + q * 72 + c8 * 8);
    *(bf16x8*)(att + ((size_t)(b * SEQ + qt * 256 + w * 32 + q)) * DMODEL + hd * HDIM + c8 * 8) = o;
  }
}

extern "C" void kernel_launch(void* const* d_in, const int* in_sizes, int n_in,
                              void* d_out, int out_size, void* d_ws, size_t ws_size,
                              hipStream_t stream) {
  (void)in_sizes; (void)n_in; (void)out_size;
  const float* x  = (const float*)d_in[0];
  const float* Wq = (const float*)d_in[1];
  const float* bq = (const float*)d_in[2];
  const float* Wk = (const float*)d_in[3];
  const float* bk = (const float*)d_in[4];
  const float* Wv = (const float*)d_in[5];
  const float* bv = (const float*)d_in[6];
  const float* Wo = (const float*)d_in[7];
  const float* bo = (const float*)d_in[8];
  float* out = (float*)d_out;

  const size_t SZ_X = (size_t)BTOK * DMODEL;  // 4M elems
  const size_t SZ_W = (size_t)DMODEL * DMODEL;
  const size_t SZ_H = (size_t)32 * SEQ * HDIM;  // B*H * S * Hd

  char* p = (char*)d_ws;
  __bf16* x_bf  = (__bf16*)p; p += SZ_X * 2;   // reused as vt after gemm<0>
  __bf16* wqkv  = (__bf16*)p; p += 3 * SZ_W * 2;
  __bf16* wo_bf = (__bf16*)p; p += SZ_W * 2;   // contiguous after wqkv (cvt4 relies on it)
  __bf16* q_bf  = (__bf16*)p; p += SZ_H * 2;
  __bf16* k_bf  = (__bf16*)p; p += SZ_H * 2;
  __bf16* v_bf  = (__bf16*)p; p += SZ_H * 2;
  __bf16* at_bf = (__bf16*)p; p += SZ_X * 2;
  if ((size_t)(p - (char*)d_ws) > ws_size) return;
  __bf16* vt_bf = x_bf;  // x dead after gemm<0>

  cvt_f32_bf16<<<(unsigned)(SZ_X / 8 / 256), 256, 0, stream>>>(x, x_bf, (int)(SZ_X / 8));
  cvt4_f32_bf16<<<dim3((unsigned)(SZ_W / 8 / 256), 4), 256, 0, stream>>>(
      Wq, Wk, Wv, Wo, wqkv, (int)(SZ_W / 8));

  gemm_bt<0><<<dim3(BTOK / 128, NQKV / 128), 256, 0, stream>>>(
      x_bf, wqkv, bq, bk, bv, q_bf, k_bf, v_bf, nullptr);
  transpose_v<<<dim3(SEQ / 64, 32), 256, 0, stream>>>(v_bf, vt_bf);
  attn_fwd<<<dim3(32, 8), 512, 0, stream>>>(q_bf, k_bf, vt_bf, at_bf);
  gemm_bt<1><<<dim3(BTOK / 128, DMODEL / 128), 256, 0, stream>>>(
      at_bf, wo_bf, bo, nullptr, nullptr, nullptr, nullptr, nullptr, out);
}

// Round 7
// 198.607 us; speedup vs baseline: 1.0153x; 1.0153x over previous
//
#include <hip/hip_runtime.h>
#include <stdint.h>

typedef __attribute__((ext_vector_type(8))) __bf16 bf16x8;
typedef __attribute__((ext_vector_type(4))) float f32x4;
typedef __attribute__((ext_vector_type(16))) float f32x16;
typedef __attribute__((ext_vector_type(4))) unsigned u32x4;

#define SEQ 2048
#define DMODEL 1024
#define NHEAD 16
#define HDIM 64
#define BTOK 4096   // B*S
#define NQKV 3072   // stacked q,k,v output cols

// ---- async global->LDS, 16B per lane; LDS dest must be wave-linear ----
__device__ __forceinline__ void gload_lds16(const __bf16* g, __bf16* l) {
  __builtin_amdgcn_global_load_lds(
      (__attribute__((address_space(1))) void*)const_cast<__bf16*>(g),
      (__attribute__((address_space(3))) void*)l, 16, 0, 0);
}

__device__ __forceinline__ f32x4 mfma16(bf16x8 a, bf16x8 b, f32x4 c) {
  return __builtin_amdgcn_mfma_f32_16x16x32_bf16(a, b, c, 0, 0, 0);
}
__device__ __forceinline__ f32x16 mfma32(bf16x8 a, bf16x8 b, f32x16 c) {
  return __builtin_amdgcn_mfma_f32_32x32x16_bf16(a, b, c, 0, 0, 0);
}

// pack 2 f32 -> 1 u32 of 2 bf16 (lo in low half)
__device__ __forceinline__ unsigned cvtpk(float lo, float hi) {
  unsigned r;
  asm("v_cvt_pk_bf16_f32 %0, %1, %2" : "=v"(r) : "v"(lo), "v"(hi));
  return r;
}
// swap a's lanes 32-63 with b's lanes 0-31 (in place)
__device__ __forceinline__ void plswap(unsigned& a, unsigned& b) {
  asm volatile("v_permlane32_swap_b32 %0, %1" : "+v"(a), "+v"(b));
}

// swizzled 16B-fragment pointer into a tile with 128B rows (64 bf16/row).
__device__ __forceinline__ const bf16x8* frag128(const __bf16* tile, int row, int c16) {
  return reinterpret_cast<const bf16x8*>(tile) + ((row << 3) + (c16 ^ (row & 7)));
}

// ---------------- fp32 -> bf16 convert, 8 elems/thread ----------------
__global__ __launch_bounds__(256) void cvt_f32_bf16(const float* __restrict__ in,
                                                    __bf16* __restrict__ out, int n8) {
  int i = blockIdx.x * 256 + threadIdx.x;
  if (i >= n8) return;
  const float4* p = reinterpret_cast<const float4*>(in) + (size_t)i * 2;
  float4 a = p[0], b = p[1];
  bf16x8 o;
  o[0] = (__bf16)a.x; o[1] = (__bf16)a.y; o[2] = (__bf16)a.z; o[3] = (__bf16)a.w;
  o[4] = (__bf16)b.x; o[5] = (__bf16)b.y; o[6] = (__bf16)b.z; o[7] = (__bf16)b.w;
  reinterpret_cast<bf16x8*>(out)[i] = o;
}

// ---- 4 weight matrices (Wq,Wk,Wv,Wo) -> contiguous bf16 in one launch ----
__global__ __launch_bounds__(256) void cvt4_f32_bf16(const float* __restrict__ w0,
                                                     const float* __restrict__ w1,
                                                     const float* __restrict__ w2,
                                                     const float* __restrict__ w3,
                                                     __bf16* __restrict__ out, int n8per) {
  const int y = blockIdx.y;
  const float* src = (y == 0) ? w0 : (y == 1) ? w1 : (y == 2) ? w2 : w3;
  int i = blockIdx.x * 256 + threadIdx.x;
  if (i >= n8per) return;
  const float4* p = reinterpret_cast<const float4*>(src) + (size_t)i * 2;
  float4 a = p[0], b = p[1];
  bf16x8 o;
  o[0] = (__bf16)a.x; o[1] = (__bf16)a.y; o[2] = (__bf16)a.z; o[3] = (__bf16)a.w;
  o[4] = (__bf16)b.x; o[5] = (__bf16)b.y; o[6] = (__bf16)b.z; o[7] = (__bf16)b.w;
  reinterpret_cast<bf16x8*>(out)[(size_t)y * n8per + i] = o;
}

// ------ C = A(4096xK) * Bw(NxK)^T + bias, 2-phase prefetch dbuf ------
// T1: bijective XCD swizzle (nwg % 8 == 0 for all our launches); per-XCD
// work ranges are bn-major contiguous -> B-slab L2 reuse.
template <int MODE>
__global__ __launch_bounds__(256) void gemm_bt(
    const __bf16* __restrict__ A, const __bf16* __restrict__ Bw,
    const float* __restrict__ bias0, const float* __restrict__ bias1,
    const float* __restrict__ bias2,
    __bf16* __restrict__ qo, __bf16* __restrict__ ko, __bf16* __restrict__ vo,
    float* __restrict__ outf) {
  constexpr int K = DMODEL;
  __shared__ __bf16 Alds[2][128][32];
  __shared__ __bf16 Blds[2][128][32];
  const int t = threadIdx.x;
  const int lane = t & 63;
  const int wr = (t >> 6) >> 1, wc = (t >> 6) & 1;
  unsigned o = blockIdx.y * gridDim.x + blockIdx.x;
  unsigned nwg = gridDim.x * gridDim.y;
  unsigned wg = (o & 7) * (nwg >> 3) + (o >> 3);  // XCD-contiguous work ranges
  const int bm0 = (int)(wg % gridDim.x) * 128, bn0 = (int)(wg / gridDim.x) * 128;

  auto stageg = [&](int k0, int buf) {
#pragma unroll
    for (int i = 0; i < 2; ++i) {
      int c = t + i * 256;               // 512 x 16B chunks per tile
      int row = c >> 2, kof = (c & 3) << 3;
      gload_lds16(A + (size_t)(bm0 + row) * K + k0 + kof, &Alds[buf][0][0] + c * 8);
      gload_lds16(Bw + (size_t)(bn0 + row) * K + k0 + kof, &Blds[buf][0][0] + c * 8);
    }
  };

  f32x4 acc[4][4] = {};
  stageg(0, 0);
  __syncthreads();
  int cur = 0;
  for (int k0 = 0; k0 < K; k0 += 32) {
    if (k0 + 32 < K) stageg(k0 + 32, cur ^ 1);  // prefetch hides under compute
    bf16x8 af[4], bfr[4];
#pragma unroll
    for (int m = 0; m < 4; ++m)
      af[m] = *(const bf16x8*)&Alds[cur][wr * 64 + m * 16 + (lane & 15)][(lane >> 4) * 8];
#pragma unroll
    for (int n = 0; n < 4; ++n)
      bfr[n] = *(const bf16x8*)&Blds[cur][wc * 64 + n * 16 + (lane & 15)][(lane >> 4) * 8];
    __builtin_amdgcn_s_setprio(1);
#pragma unroll
    for (int m = 0; m < 4; ++m)
#pragma unroll
      for (int n = 0; n < 4; ++n)
        acc[m][n] = mfma16(af[m], bfr[n], acc[m][n]);
    __builtin_amdgcn_s_setprio(0);
    __syncthreads();  // drains prefetch vmcnt + protects buffer reuse
    cur ^= 1;
  }

  const int r0 = bm0 + wr * 64, c0 = bn0 + wc * 64;
#pragma unroll
  for (int m = 0; m < 4; ++m) {
#pragma unroll
    for (int n = 0; n < 4; ++n) {
#pragma unroll
      for (int r = 0; r < 4; ++r) {
        int gm = r0 + m * 16 + (lane >> 4) * 4 + r;  // token
        int gn = c0 + n * 16 + (lane & 15);          // output col
        float v = acc[m][n][r];
        if (MODE == 0) {
          int which = gn >> 10, j = gn & 1023;
          int h = j >> 6, d = j & 63;
          int b = gm >> 11, s = gm & 2047;
          size_t off = ((size_t)(b * NHEAD + h) * SEQ + s) * HDIM + d;
          if (which == 0)
            qo[off] = (__bf16)(v + bias0[j]);
          else if (which == 1)
            ko[off] = (__bf16)(v + bias1[j]);
          else
            vo[off] = (__bf16)(v + bias2[j]);
        } else {
          outf[(size_t)gm * DMODEL + gn] = v + bias0[gn];
        }
      }
    }
  }
}

// ------- v (BH,S,Hd) -> vt (BH,Hd,S), LDS-tiled 64x64 transpose -------
__global__ __launch_bounds__(256) void transpose_v(const __bf16* __restrict__ v,
                                                   __bf16* __restrict__ vt) {
  __shared__ __bf16 T[64][80];
  const int s0 = blockIdx.x * 64;
  const int bh = blockIdx.y;
  const int t = threadIdx.x;
  const __bf16* src = v + ((size_t)bh * SEQ + s0) * HDIM;
#pragma unroll
  for (int p = 0; p < 2; ++p) {
    int c = t + p * 256;
    int r = c >> 3, d0 = (c & 7) << 3;
    *(bf16x8*)&T[r][d0] = *(const bf16x8*)(src + (size_t)r * HDIM + d0);
  }
  __syncthreads();
#pragma unroll
  for (int p = 0; p < 2; ++p) {
    int c = t + p * 256;
    int d = c & 63, sc = (c >> 6) << 3;
    bf16x8 o;
#pragma unroll
    for (int j = 0; j < 8; ++j) o[j] = T[sc + j][d];
    *(bf16x8*)(vt + ((size_t)bh * HDIM + d) * SEQ + s0 + sc) = o;
  }
}

// --------- flash attention: 8 waves x 32 q = QBLK 256, KVBLK 64 ---------
// mode 1 (key-split): grid.y = 12. yy<4: qt=yy part0 keys [4qt, 2qt+16);
// yy in 4..7: qt=yy-4 part1 keys [2qt+16, 32); yy in 8..11: qt=yy-4 full.
// Split blocks write normalized partial O (bf16) + (m,l); merge recombines.
// mode 0 (fallback, small ws): grid.y = 8, all full.
__global__ __launch_bounds__(512) void attn_fwd(const __bf16* __restrict__ qg,
                                                const __bf16* __restrict__ kg,
                                                const __bf16* __restrict__ vtg,
                                                __bf16* __restrict__ att,
                                                __bf16* __restrict__ part,
                                                float2* __restrict__ mlb,
                                                int mode) {
  __shared__ __align__(16) char smem[36864];  // loop: K[2]8K|V[2]8K=32K; epi: 8x32x72 bf16
  const int t = threadIdx.x, lane = t & 63, w = t >> 6, hi = lane >> 5;
  const int bh = blockIdx.x;
  const int yy = blockIdx.y;
  constexpr int NT = SEQ / 64;
  int qt, ktA, ktB, pr = 0;
  bool full;
  if (mode == 0) {
    qt = yy; ktA = qt * 4; ktB = NT; full = true;
  } else if (yy < 4) {
    qt = yy; ktA = qt * 4; ktB = 2 * qt + 16; full = false; pr = 0;
  } else if (yy < 8) {
    qt = yy - 4; ktA = 2 * qt + 16; ktB = NT; full = false; pr = 1;
  } else {
    qt = yy - 4; ktA = qt * 4; ktB = NT; full = true;
  }
  const int q0w = qt * 256 + w * 32;
  const int qabs = q0w + (lane & 31);
  const bool diagBlock = (ktA == qt * 4);
  const int ktw = diagBlock ? (q0w >> 6) : ktA;  // first tile this wave computes

  const __bf16* kbase = kg + (size_t)bh * SEQ * HDIM;
  const __bf16* vbase = vtg + (size_t)bh * HDIM * SEQ;

  // Q straight to registers, B-operand layout: col q = lane&31, rows d
  bf16x8 qf[4];
  {
    const __bf16* qptr = qg + ((size_t)bh * SEQ + qabs) * HDIM + hi * 8;
#pragma unroll
    for (int ds = 0; ds < 4; ++ds) qf[ds] = *(const bf16x8*)(qptr + ds * 16);
  }

  // one K chunk + one V chunk per thread per tile (512 x 16B = 8KB each)
  auto stage = [&](int kt_, int buf) {
    int row = t >> 3, sc = (t & 7) ^ (row & 7);
    gload_lds16(kbase + ((size_t)kt_ * 64 + row) * HDIM + sc * 8,
                (__bf16*)(smem + buf * 8192) + t * 8);
    gload_lds16(vbase + (size_t)row * SEQ + kt_ * 64 + sc * 8,
                (__bf16*)(smem + 16384 + buf * 8192) + t * 8);
  };

  f32x16 acc0 = {}, acc1 = {};
  float m = -3.0e38f, l = 0.f;
  const float kScale = 0.03125f;  // 1/sqrt(1024)

  stage(ktA, 0);
  __syncthreads();
  int cur = 0;

  for (int kt = ktA; kt < ktB; ++kt) {
    if (kt + 1 < ktB) stage(kt + 1, cur ^ 1);  // prefetch under this tile's compute
    if (kt >= ktw) {
      const __bf16* Kt = (const __bf16*)(smem + cur * 8192);
      const __bf16* Vw = (const __bf16*)(smem + 16384 + cur * 8192);

      // S^T[key][q] = K · Q^T : two 32-key halves
      f32x16 s0 = {}, s1 = {};
      __builtin_amdgcn_s_setprio(1);
#pragma unroll
      for (int ds = 0; ds < 4; ++ds) {
        s0 = mfma32(*frag128(Kt, lane & 31, 2 * ds + hi), qf[ds], s0);
        s1 = mfma32(*frag128(Kt, 32 + (lane & 31), 2 * ds + hi), qf[ds], s1);
      }
      __builtin_amdgcn_s_setprio(0);

      // causal mask (keep key >= q): only this wave's diagonal tile is partial
      if (diagBlock && kt == ktw) {
#pragma unroll
        for (int r = 0; r < 16; ++r) {
          int krow = (r & 3) + 8 * (r >> 2) + 4 * hi;
          if (kt * 64 + krow < qabs) s0[r] = -3.0e38f;
          if (kt * 64 + 32 + krow < qabs) s1[r] = -3.0e38f;
        }
      }

      // max: depth-5 tree + one cross-half swap
      float mt[8];
#pragma unroll
      for (int r = 0; r < 8; ++r)
        mt[r] = fmaxf(fmaxf(s0[r], s0[r + 8]), fmaxf(s1[r], s1[r + 8]));
#pragma unroll
      for (int r = 0; r < 4; ++r) mt[r] = fmaxf(mt[r], mt[r + 4]);
      float pmax = fmaxf(fmaxf(mt[0], mt[2]), fmaxf(mt[1], mt[3]));
      pmax = fmaxf(pmax, __shfl_xor(pmax, 32));

      // T13 defer-max, wave-uniform: rescale only if max grew > 256 raw (= e^8)
      if (!__all(pmax - m <= 256.0f)) {
        float newm = fmaxf(m, pmax);
        float corr = __expf((m - newm) * kScale);
        m = newm;
        l *= corr;
#pragma unroll
        for (int r = 0; r < 16; ++r) { acc0[r] *= corr; acc1[r] *= corr; }
      }
      const float bias = m * kScale;
#pragma unroll
      for (int r = 0; r < 16; ++r) s0[r] = __expf(fmaf(s0[r], kScale, -bias));
#pragma unroll
      for (int r = 0; r < 16; ++r) s1[r] = __expf(fmaf(s1[r], kScale, -bias));
      // sum: depth-5 tree (float add not reassociable -> hand-tree)
      float ut[8];
#pragma unroll
      for (int r = 0; r < 8; ++r) ut[r] = (s0[r] + s0[r + 8]) + (s1[r] + s1[r + 8]);
#pragma unroll
      for (int r = 0; r < 4; ++r) ut[r] += ut[r + 4];
      float sum = (ut[0] + ut[2]) + (ut[1] + ut[3]);
      sum += __shfl_xor(sum, 32);
      l += sum;

      // repack P (C-layout f32) -> B-operand bf16 frags: cvt_pk + permlane32_swap
      bf16x8 pb[2][2];
#pragma unroll
      for (int h = 0; h < 2; ++h) {
#pragma unroll
        for (int ks = 0; ks < 2; ++ks) {
          int o = ks * 8;
          unsigned a, b, c, d;
          if (h == 0) {
            a = cvtpk(s0[o + 0], s0[o + 1]); b = cvtpk(s0[o + 4], s0[o + 5]);
            c = cvtpk(s0[o + 2], s0[o + 3]); d = cvtpk(s0[o + 6], s0[o + 7]);
          } else {
            a = cvtpk(s1[o + 0], s1[o + 1]); b = cvtpk(s1[o + 4], s1[o + 5]);
            c = cvtpk(s1[o + 2], s1[o + 3]); d = cvtpk(s1[o + 6], s1[o + 7]);
          }
          plswap(a, b);
          plswap(c, d);
          union { u32x4 u; bf16x8 v; } f;
          f.u[0] = a; f.u[1] = c; f.u[2] = b; f.u[3] = d;
          pb[h][ks] = f.v;
        }
      }

      // O^T[d][q] += V^T · P^T
      __builtin_amdgcn_s_setprio(1);
#pragma unroll
      for (int h = 0; h < 2; ++h)
#pragma unroll
        for (int ks = 0; ks < 2; ++ks) {
          int cc = h * 4 + ks * 2 + hi;
          acc0 = mfma32(*frag128(Vw, lane & 31, cc), pb[h][ks], acc0);
          acc1 = mfma32(*frag128(Vw, 32 + (lane & 31), cc), pb[h][ks], acc1);
        }
      __builtin_amdgcn_s_setprio(0);
    }
    __syncthreads();  // drains prefetch, protects buffer swap
    cur ^= 1;
  }

  // epilogue: O^T (normalized) -> per-wave bf16 LDS [32][72] -> coalesced stores
  float inv = 1.0f / l;
  __bf16* Ob = (__bf16*)smem + (size_t)w * (32 * 72);
#pragma unroll
  for (int r = 0; r < 16; ++r) {
    int d = (r & 3) + 8 * (r >> 2) + 4 * hi;
    Ob[(lane & 31) * 72 + d] = (__bf16)(acc0[r] * inv);
    Ob[(lane & 31) * 72 + 32 + d] = (__bf16)(acc1[r] * inv);
  }
  if (full) {
    const int b = bh >> 4, hd = bh & 15;
#pragma unroll
    for (int j = 0; j < 4; ++j) {
      int f = j * 64 + lane;
      int q = f >> 3, c8 = f & 7;
      bf16x8 o = *(const bf16x8*)(Ob + q * 72 + c8 * 8);
      *(bf16x8*)(att + ((size_t)(b * SEQ + qt * 256 + w * 32 + q)) * DMODEL + hd * HDIM + c8 * 8) = o;
    }
  } else {
    __bf16* dst = part + ((((size_t)pr * 32 + bh) * 4 + qt) * 256 + w * 32) * 64;
#pragma unroll
    for (int j = 0; j < 4; ++j) {
      int f = j * 64 + lane;
      int q = f >> 3, c8 = f & 7;
      *(bf16x8*)(dst + (size_t)q * 64 + c8 * 8) = *(const bf16x8*)(Ob + q * 72 + c8 * 8);
    }
    if ((lane & 32) == 0)
      mlb[(((size_t)pr * 32 + bh) * 4 + qt) * 256 + w * 32 + (lane & 31)] = make_float2(m, l);
  }
}

// -------- merge two key-split partials for q-rows < 1024 of each bh --------
__global__ __launch_bounds__(256) void attn_merge(const __bf16* __restrict__ part,
                                                  const float2* __restrict__ mlb,
                                                  __bf16* __restrict__ att) {
  int flat = blockIdx.x * 256 + threadIdx.x;  // 32 bh x 1024 q x 8 d-chunks
  int bh = flat >> 13;
  int rem = flat & 8191;
  int gq = rem >> 3, c8 = rem & 7;
  size_t idx1 = ((size_t)bh * 4 + (gq >> 8)) * 256 + (gq & 255);
  size_t idx2 = idx1 + (size_t)32 * 4 * 256;
  float2 a = mlb[idx1], b2 = mlb[idx2];
  float m = fmaxf(a.x, b2.x);
  float w1 = __expf((a.x - m) * 0.03125f) * a.y;
  float w2 = __expf((b2.x - m) * 0.03125f) * b2.y;
  float inv = 1.0f / (w1 + w2);
  float r1 = w1 * inv, r2 = w2 * inv;
  bf16x8 o1 = *(const bf16x8*)(part + idx1 * 64 + c8 * 8);
  bf16x8 o2 = *(const bf16x8*)(part + idx2 * 64 + c8 * 8);
  bf16x8 o;
#pragma unroll
  for (int e = 0; e < 8; ++e)
    o[e] = (__bf16)(r1 * (float)o1[e] + r2 * (float)o2[e]);
  int b = bh >> 4, hd = bh & 15;
  *(bf16x8*)(att + ((size_t)(b * SEQ + gq)) * DMODEL + hd * HDIM + c8 * 8) = o;
}

extern "C" void kernel_launch(void* const* d_in, const int* in_sizes, int n_in,
                              void* d_out, int out_size, void* d_ws, size_t ws_size,
                              hipStream_t stream) {
  (void)in_sizes; (void)n_in; (void)out_size;
  const float* x  = (const float*)d_in[0];
  const float* Wq = (const float*)d_in[1];
  const float* bq = (const float*)d_in[2];
  const float* Wk = (const float*)d_in[3];
  const float* bk = (const float*)d_in[4];
  const float* Wv = (const float*)d_in[5];
  const float* bv = (const float*)d_in[6];
  const float* Wo = (const float*)d_in[7];
  const float* bo = (const float*)d_in[8];
  float* out = (float*)d_out;

  const size_t SZ_X = (size_t)BTOK * DMODEL;  // 4M elems
  const size_t SZ_W = (size_t)DMODEL * DMODEL;
  const size_t SZ_H = (size_t)32 * SEQ * HDIM;  // B*H * S * Hd

  char* p = (char*)d_ws;
  __bf16* x_bf  = (__bf16*)p; p += SZ_X * 2;   // reused as vt after gemm<0>
  __bf16* wqkv  = (__bf16*)p; p += 3 * SZ_W * 2;
  __bf16* wo_bf = (__bf16*)p; p += SZ_W * 2;   // contiguous after wqkv (cvt4 relies on it)
  __bf16* q_bf  = (__bf16*)p; p += SZ_H * 2;
  __bf16* k_bf  = (__bf16*)p; p += SZ_H * 2;
  __bf16* v_bf  = (__bf16*)p; p += SZ_H * 2;
  __bf16* at_bf = (__bf16*)p; p += SZ_X * 2;
  if ((size_t)(p - (char*)d_ws) > ws_size) return;
  __bf16* vt_bf = x_bf;  // x dead after gemm<0>

  // key-split partial buffers (mode 1): 16MB O + 2MB (m,l)
  __bf16* part = (__bf16*)p; p += (size_t)2 * 32 * 4 * 256 * 64 * 2;
  float2* mlb  = (float2*)p; p += (size_t)2 * 32 * 4 * 256 * sizeof(float2);
  const int mode = ((size_t)(p - (char*)d_ws) <= ws_size) ? 1 : 0;

  cvt_f32_bf16<<<(unsigned)(SZ_X / 8 / 256), 256, 0, stream>>>(x, x_bf, (int)(SZ_X / 8));
  cvt4_f32_bf16<<<dim3((unsigned)(SZ_W / 8 / 256), 4), 256, 0, stream>>>(
      Wq, Wk, Wv, Wo, wqkv, (int)(SZ_W / 8));

  gemm_bt<0><<<dim3(BTOK / 128, NQKV / 128), 256, 0, stream>>>(
      x_bf, wqkv, bq, bk, bv, q_bf, k_bf, v_bf, nullptr);
  transpose_v<<<dim3(SEQ / 64, 32), 256, 0, stream>>>(v_bf, vt_bf);
  attn_fwd<<<dim3(32, mode ? 12 : 8), 512, 0, stream>>>(q_bf, k_bf, vt_bf, at_bf,
                                                        part, mlb, mode);
  if (mode)
    attn_merge<<<1024, 256, 0, stream>>>(part, mlb, at_bf);
  gemm_bt<1><<<dim3(BTOK / 128, DMODEL / 128), 256, 0, stream>>>(
      at_bf, wo_bf, bo, nullptr, nullptr, nullptr, nullptr, nullptr, out);
}

// Round 9
// 190.339 us; speedup vs baseline: 1.0594x; 1.0434x over previous
//
#include <hip/hip_runtime.h>
#include <stdint.h>

typedef __attribute__((ext_vector_type(8))) __bf16 bf16x8;
typedef __attribute__((ext_vector_type(4))) float f32x4;
typedef __attribute__((ext_vector_type(16))) float f32x16;
typedef __attribute__((ext_vector_type(4))) unsigned u32x4;

#define SEQ 2048
#define DMODEL 1024
#define NHEAD 16
#define HDIM 64
#define BTOK 4096   // B*S
#define NQKV 3072   // stacked q,k,v output cols
#define NJOB 27     // causal work queue: jobs per bh, each <= 6 key-tiles

// ---- async global->LDS, 16B per lane; LDS dest must be wave-linear ----
__device__ __forceinline__ void gload_lds16(const __bf16* g, __bf16* l) {
  __builtin_amdgcn_global_load_lds(
      (__attribute__((address_space(1))) void*)const_cast<__bf16*>(g),
      (__attribute__((address_space(3))) void*)l, 16, 0, 0);
}

__device__ __forceinline__ f32x4 mfma16(bf16x8 a, bf16x8 b, f32x4 c) {
  return __builtin_amdgcn_mfma_f32_16x16x32_bf16(a, b, c, 0, 0, 0);
}
__device__ __forceinline__ f32x16 mfma32(bf16x8 a, bf16x8 b, f32x16 c) {
  return __builtin_amdgcn_mfma_f32_32x32x16_bf16(a, b, c, 0, 0, 0);
}

// pack 2 f32 -> 1 u32 of 2 bf16 (lo in low half)
__device__ __forceinline__ unsigned cvtpk(float lo, float hi) {
  unsigned r;
  asm("v_cvt_pk_bf16_f32 %0, %1, %2" : "=v"(r) : "v"(lo), "v"(hi));
  return r;
}
// swap a's lanes 32-63 with b's lanes 0-31 (in place)
__device__ __forceinline__ void plswap(unsigned& a, unsigned& b) {
  asm volatile("v_permlane32_swap_b32 %0, %1" : "+v"(a), "+v"(b));
}

// swizzled 16B-fragment pointer into a tile with 128B rows (64 bf16/row).
__device__ __forceinline__ const bf16x8* frag128(const __bf16* tile, int row, int c16) {
  return reinterpret_cast<const bf16x8*>(tile) + ((row << 3) + (c16 ^ (row & 7)));
}

// causal job table: per bh, 27 jobs of <= 6 key-tiles (balanced within qt)
__device__ const int JOB_QT[NJOB] = {0,0,0,0,0,0, 1,1,1,1,1, 2,2,2,2, 3,3,3,3, 4,4,4, 5,5, 6,6, 7};
__device__ const int JOB_A[NJOB]  = {0,6,12,17,22,27, 4,10,16,22,27, 8,14,20,26, 12,17,22,27, 16,22,27, 20,26, 24,28, 28};
__device__ const int JOB_B[NJOB]  = {6,12,17,22,27,32, 10,16,22,27,32, 14,20,26,32, 17,22,27,32, 22,27,32, 26,32, 28,32, 32};
__device__ const int JSTART[8] = {0,6,11,15,19,22,24,26};
__device__ const int NPARTQ[8] = {6,5,4,4,3,2,2,1};

// ---------------- fp32 -> bf16 convert, 8 elems/thread ----------------
__global__ __launch_bounds__(256) void cvt_f32_bf16(const float* __restrict__ in,
                                                    __bf16* __restrict__ out, int n8) {
  int i = blockIdx.x * 256 + threadIdx.x;
  if (i >= n8) return;
  const float4* p = reinterpret_cast<const float4*>(in) + (size_t)i * 2;
  float4 a = p[0], b = p[1];
  bf16x8 o;
  o[0] = (__bf16)a.x; o[1] = (__bf16)a.y; o[2] = (__bf16)a.z; o[3] = (__bf16)a.w;
  o[4] = (__bf16)b.x; o[5] = (__bf16)b.y; o[6] = (__bf16)b.z; o[7] = (__bf16)b.w;
  reinterpret_cast<bf16x8*>(out)[i] = o;
}

// ---- 4 weight matrices (Wq,Wk,Wv,Wo) -> contiguous bf16 in one launch ----
__global__ __launch_bounds__(256) void cvt4_f32_bf16(const float* __restrict__ w0,
                                                     const float* __restrict__ w1,
                                                     const float* __restrict__ w2,
                                                     const float* __restrict__ w3,
                                                     __bf16* __restrict__ out, int n8per) {
  const int y = blockIdx.y;
  const float* src = (y == 0) ? w0 : (y == 1) ? w1 : (y == 2) ? w2 : w3;
  int i = blockIdx.x * 256 + threadIdx.x;
  if (i >= n8per) return;
  const float4* p = reinterpret_cast<const float4*>(src) + (size_t)i * 2;
  float4 a = p[0], b = p[1];
  bf16x8 o;
  o[0] = (__bf16)a.x; o[1] = (__bf16)a.y; o[2] = (__bf16)a.z; o[3] = (__bf16)a.w;
  o[4] = (__bf16)b.x; o[5] = (__bf16)b.y; o[6] = (__bf16)b.z; o[7] = (__bf16)b.w;
  reinterpret_cast<bf16x8*>(out)[(size_t)y * n8per + i] = o;
}

// ------ C = A(4096xK) * Bw(NxK)^T + bias, 2-phase prefetch dbuf ------
// MODE 0: BN=128, N=3072, scatter q,k,v (B,H,S,Hd) bf16. grid 32x24.
// MODE 1: BN=64,  N=1024, fp32 out + bias. grid 32x16 (2 blocks/CU).
// XCD swizzle: 2-D per-XCD tile groups sized to ~L2 (8bm x 12bn / 8bm x 8bn).
template <int MODE, int BN>
__global__ __launch_bounds__(256) void gemm_bt(
    const __bf16* __restrict__ A, const __bf16* __restrict__ Bw,
    const float* __restrict__ bias0, const float* __restrict__ bias1,
    const float* __restrict__ bias2,
    __bf16* __restrict__ qo, __bf16* __restrict__ ko, __bf16* __restrict__ vo,
    float* __restrict__ outf) {
  constexpr int K = DMODEL;
  constexpr int NF = BN / 32;   // n-frags per wave (wave covers BN/2 cols)
  __shared__ __bf16 Alds[2][128][32];
  __shared__ __bf16 Blds[2][BN][32];
  const int t = threadIdx.x;
  const int lane = t & 63;
  const int wr = (t >> 6) >> 1, wc = (t >> 6) & 1;
  unsigned o = blockIdx.y * gridDim.x + blockIdx.x;
  unsigned xc = o & 7, j = o >> 3;
  int bm0, bn0;
  if constexpr (MODE == 0) {       // 768 wgs: XCD gets 8bm x 12bn (2MB+3MB)
    bm0 = (int)((xc & 3) * 8 + (j & 7)) * 128;
    bn0 = (int)((xc >> 2) * 12 + (j >> 3)) * 128;
  } else {                         // 512 wgs: XCD gets 8bm x 8bn (2MB+1MB)
    bm0 = (int)((xc & 3) * 8 + (j & 7)) * 128;
    bn0 = (int)((xc >> 2) * 8 + (j >> 3)) * 64;
  }

  auto stageg = [&](int k0, int buf) {
#pragma unroll
    for (int i = 0; i < 2; ++i) {
      int c = t + i * 256;               // A: 512 x 16B chunks
      int row = c >> 2, kof = (c & 3) << 3;
      gload_lds16(A + (size_t)(bm0 + row) * K + k0 + kof, &Alds[buf][0][0] + c * 8);
    }
#pragma unroll
    for (int i = 0; i < BN * 4 / 256; ++i) {
      int c = t + i * 256;               // B: BN*4 x 16B chunks
      int row = c >> 2, kof = (c & 3) << 3;
      gload_lds16(Bw + (size_t)(bn0 + row) * K + k0 + kof, &Blds[buf][0][0] + c * 8);
    }
  };

  f32x4 acc[4][NF] = {};
  stageg(0, 0);
  __syncthreads();
  int cur = 0;
  for (int k0 = 0; k0 < K; k0 += 32) {
    if (k0 + 32 < K) stageg(k0 + 32, cur ^ 1);  // prefetch hides under compute
    bf16x8 af[4], bfr[NF];
#pragma unroll
    for (int m = 0; m < 4; ++m)
      af[m] = *(const bf16x8*)&Alds[cur][wr * 64 + m * 16 + (lane & 15)][(lane >> 4) * 8];
#pragma unroll
    for (int n = 0; n < NF; ++n)
      bfr[n] = *(const bf16x8*)&Blds[cur][wc * (BN / 2) + n * 16 + (lane & 15)][(lane >> 4) * 8];
    __builtin_amdgcn_s_setprio(1);
#pragma unroll
    for (int m = 0; m < 4; ++m)
#pragma unroll
      for (int n = 0; n < NF; ++n)
        acc[m][n] = mfma16(af[m], bfr[n], acc[m][n]);
    __builtin_amdgcn_s_setprio(0);
    __syncthreads();  // drains prefetch vmcnt + protects buffer reuse
    cur ^= 1;
  }

  const int r0 = bm0 + wr * 64, c0 = bn0 + wc * (BN / 2);
#pragma unroll
  for (int m = 0; m < 4; ++m) {
#pragma unroll
    for (int n = 0; n < NF; ++n) {
#pragma unroll
      for (int r = 0; r < 4; ++r) {
        int gm = r0 + m * 16 + (lane >> 4) * 4 + r;  // token
        int gn = c0 + n * 16 + (lane & 15);          // output col
        float v = acc[m][n][r];
        if (MODE == 0) {
          int which = gn >> 10, jj = gn & 1023;
          int h = jj >> 6, d = jj & 63;
          int b = gm >> 11, s = gm & 2047;
          size_t off = ((size_t)(b * NHEAD + h) * SEQ + s) * HDIM + d;
          if (which == 0)
            qo[off] = (__bf16)(v + bias0[jj]);
          else if (which == 1)
            ko[off] = (__bf16)(v + bias1[jj]);
          else
            vo[off] = (__bf16)(v + bias2[jj]);
        } else {
          outf[(size_t)gm * DMODEL + gn] = v + bias0[gn];
        }
      }
    }
  }
}

// ------- v (BH,S,Hd) -> vt (BH,Hd,S), LDS-tiled 64x64 transpose -------
__global__ __launch_bounds__(256) void transpose_v(const __bf16* __restrict__ v,
                                                   __bf16* __restrict__ vt) {
  __shared__ __bf16 T[64][80];
  const int s0 = blockIdx.x * 64;
  const int bh = blockIdx.y;
  const int t = threadIdx.x;
  const __bf16* src = v + ((size_t)bh * SEQ + s0) * HDIM;
#pragma unroll
  for (int p = 0; p < 2; ++p) {
    int c = t + p * 256;
    int r = c >> 3, d0 = (c & 7) << 3;
    *(bf16x8*)&T[r][d0] = *(const bf16x8*)(src + (size_t)r * HDIM + d0);
  }
  __syncthreads();
#pragma unroll
  for (int p = 0; p < 2; ++p) {
    int c = t + p * 256;
    int d = c & 63, sc = (c >> 6) << 3;
    bf16x8 o;
#pragma unroll
    for (int jj = 0; jj < 8; ++jj) o[jj] = T[sc + jj][d];
    *(bf16x8*)(vt + ((size_t)bh * HDIM + d) * SEQ + s0 + sc) = o;
  }
}

// --------- flash attention: 8 waves x 32 q = QBLK 256, KVBLK 64 ---------
// mode 1: grid.y = NJOB jobs (<=6 key-tiles each, 864 blocks ~3.4/CU); every
// job writes a normalized bf16 partial + (m,l); merge kernel recombines.
// mode 0 (fallback, small ws): grid.y = 8, full key range, direct store.
__global__ __launch_bounds__(512) void attn_fwd(const __bf16* __restrict__ qg,
                                                const __bf16* __restrict__ kg,
                                                const __bf16* __restrict__ vtg,
                                                __bf16* __restrict__ att,
                                                __bf16* __restrict__ part,
                                                float2* __restrict__ mlb,
                                                int mode) {
  __shared__ __align__(16) char smem[36864];  // loop: K[2]8K|V[2]8K; epi: 8x32x72 bf16
  const int t = threadIdx.x, lane = t & 63, w = t >> 6, hi = lane >> 5;
  const int bh = blockIdx.x;
  const int yy = blockIdx.y;
  constexpr int NT = SEQ / 64;
  int qt, ktA, ktB;
  if (mode) { qt = JOB_QT[yy]; ktA = JOB_A[yy]; ktB = JOB_B[yy]; }
  else      { qt = yy; ktA = qt * 4; ktB = NT; }
  const bool full = (mode == 0);
  const bool diagBlock = (ktA == qt * 4);
  const int q0w = qt * 256 + w * 32;
  const int qabs = q0w + (lane & 31);
  const int ktw = diagBlock ? (q0w >> 6) : ktA;  // first tile this wave computes

  const __bf16* kbase = kg + (size_t)bh * SEQ * HDIM;
  const __bf16* vbase = vtg + (size_t)bh * HDIM * SEQ;

  // Q straight to registers, B-operand layout: col q = lane&31, rows d
  bf16x8 qf[4];
  {
    const __bf16* qptr = qg + ((size_t)bh * SEQ + qabs) * HDIM + hi * 8;
#pragma unroll
    for (int ds = 0; ds < 4; ++ds) qf[ds] = *(const bf16x8*)(qptr + ds * 16);
  }

  // one K chunk + one V chunk per thread per tile (512 x 16B = 8KB each)
  auto stage = [&](int kt_, int buf) {
    int row = t >> 3, sc = (t & 7) ^ (row & 7);
    gload_lds16(kbase + ((size_t)kt_ * 64 + row) * HDIM + sc * 8,
                (__bf16*)(smem + buf * 8192) + t * 8);
    gload_lds16(vbase + (size_t)row * SEQ + kt_ * 64 + sc * 8,
                (__bf16*)(smem + 16384 + buf * 8192) + t * 8);
  };

  f32x16 acc0 = {}, acc1 = {};
  float m = -3.0e38f, l = 0.f;
  const float kScale = 0.03125f;  // 1/sqrt(1024)

  stage(ktA, 0);
  __syncthreads();
  int cur = 0;

  for (int kt = ktA; kt < ktB; ++kt) {
    if (kt + 1 < ktB) stage(kt + 1, cur ^ 1);  // prefetch under this tile's compute
    if (kt >= ktw) {
      const __bf16* Kt = (const __bf16*)(smem + cur * 8192);
      const __bf16* Vw = (const __bf16*)(smem + 16384 + cur * 8192);

      // S^T[key][q] = K · Q^T : two 32-key halves
      f32x16 s0 = {}, s1 = {};
      __builtin_amdgcn_s_setprio(1);
#pragma unroll
      for (int ds = 0; ds < 4; ++ds) {
        s0 = mfma32(*frag128(Kt, lane & 31, 2 * ds + hi), qf[ds], s0);
        s1 = mfma32(*frag128(Kt, 32 + (lane & 31), 2 * ds + hi), qf[ds], s1);
      }
      __builtin_amdgcn_s_setprio(0);

      // causal mask (keep key >= q): only this wave's diagonal tile is partial
      if (diagBlock && kt == ktw) {
#pragma unroll
        for (int r = 0; r < 16; ++r) {
          int krow = (r & 3) + 8 * (r >> 2) + 4 * hi;
          if (kt * 64 + krow < qabs) s0[r] = -3.0e38f;
          if (kt * 64 + 32 + krow < qabs) s1[r] = -3.0e38f;
        }
      }

      // max: depth-5 tree + one cross-half swap
      float mt[8];
#pragma unroll
      for (int r = 0; r < 8; ++r)
        mt[r] = fmaxf(fmaxf(s0[r], s0[r + 8]), fmaxf(s1[r], s1[r + 8]));
#pragma unroll
      for (int r = 0; r < 4; ++r) mt[r] = fmaxf(mt[r], mt[r + 4]);
      float pmax = fmaxf(fmaxf(mt[0], mt[2]), fmaxf(mt[1], mt[3]));
      pmax = fmaxf(pmax, __shfl_xor(pmax, 32));

      // T13 defer-max, wave-uniform: rescale only if max grew > 256 raw (= e^8)
      if (!__all(pmax - m <= 256.0f)) {
        float newm = fmaxf(m, pmax);
        float corr = __expf((m - newm) * kScale);
        m = newm;
        l *= corr;
#pragma unroll
        for (int r = 0; r < 16; ++r) { acc0[r] *= corr; acc1[r] *= corr; }
      }
      const float bias = m * kScale;
#pragma unroll
      for (int r = 0; r < 16; ++r) s0[r] = __expf(fmaf(s0[r], kScale, -bias));
#pragma unroll
      for (int r = 0; r < 16; ++r) s1[r] = __expf(fmaf(s1[r], kScale, -bias));
      // sum: depth-5 tree (float add not reassociable -> hand-tree)
      float ut[8];
#pragma unroll
      for (int r = 0; r < 8; ++r) ut[r] = (s0[r] + s0[r + 8]) + (s1[r] + s1[r + 8]);
#pragma unroll
      for (int r = 0; r < 4; ++r) ut[r] += ut[r + 4];
      float sum = (ut[0] + ut[2]) + (ut[1] + ut[3]);
      sum += __shfl_xor(sum, 32);
      l += sum;

      // repack P (C-layout f32) -> B-operand bf16 frags: cvt_pk + permlane32_swap
      bf16x8 pb[2][2];
#pragma unroll
      for (int h = 0; h < 2; ++h) {
#pragma unroll
        for (int ks = 0; ks < 2; ++ks) {
          int o = ks * 8;
          unsigned a, b, c, d;
          if (h == 0) {
            a = cvtpk(s0[o + 0], s0[o + 1]); b = cvtpk(s0[o + 4], s0[o + 5]);
            c = cvtpk(s0[o + 2], s0[o + 3]); d = cvtpk(s0[o + 6], s0[o + 7]);
          } else {
            a = cvtpk(s1[o + 0], s1[o + 1]); b = cvtpk(s1[o + 4], s1[o + 5]);
            c = cvtpk(s1[o + 2], s1[o + 3]); d = cvtpk(s1[o + 6], s1[o + 7]);
          }
          plswap(a, b);
          plswap(c, d);
          union { u32x4 u; bf16x8 v; } f;
          f.u[0] = a; f.u[1] = c; f.u[2] = b; f.u[3] = d;
          pb[h][ks] = f.v;
        }
      }

      // O^T[d][q] += V^T · P^T
      __builtin_amdgcn_s_setprio(1);
#pragma unroll
      for (int h = 0; h < 2; ++h)
#pragma unroll
        for (int ks = 0; ks < 2; ++ks) {
          int cc = h * 4 + ks * 2 + hi;
          acc0 = mfma32(*frag128(Vw, lane & 31, cc), pb[h][ks], acc0);
          acc1 = mfma32(*frag128(Vw, 32 + (lane & 31), cc), pb[h][ks], acc1);
        }
      __builtin_amdgcn_s_setprio(0);
    }
    __syncthreads();  // drains prefetch, protects buffer swap
    cur ^= 1;
  }

  // epilogue: O^T (normalized) -> per-wave bf16 LDS [32][72] -> coalesced stores
  float inv = (l > 0.f) ? 1.0f / l : 0.f;
  __bf16* Ob = (__bf16*)smem + (size_t)w * (32 * 72);
#pragma unroll
  for (int r = 0; r < 16; ++r) {
    int d = (r & 3) + 8 * (r >> 2) + 4 * hi;
    Ob[(lane & 31) * 72 + d] = (__bf16)(acc0[r] * inv);
    Ob[(lane & 31) * 72 + 32 + d] = (__bf16)(acc1[r] * inv);
  }
  if (full) {
    const int b = bh >> 4, hd = bh & 15;
#pragma unroll
    for (int jj = 0; jj < 4; ++jj) {
      int f = jj * 64 + lane;
      int q = f >> 3, c8 = f & 7;
      bf16x8 o = *(const bf16x8*)(Ob + q * 72 + c8 * 8);
      *(bf16x8*)(att + ((size_t)(b * SEQ + qt * 256 + w * 32 + q)) * DMODEL + hd * HDIM + c8 * 8) = o;
    }
  } else {
    size_t jidx = (size_t)bh * NJOB + yy;
    __bf16* dst = part + (jidx * 256 + w * 32) * 64;
#pragma unroll
    for (int jj = 0; jj < 4; ++jj) {
      int f = jj * 64 + lane;
      int q = f >> 3, c8 = f & 7;
      *(bf16x8*)(dst + (size_t)q * 64 + c8 * 8) = *(const bf16x8*)(Ob + q * 72 + c8 * 8);
    }
    if ((lane & 32) == 0)
      mlb[jidx * 256 + w * 32 + (lane & 31)] = make_float2(m, l);
  }
}

// ------ merge 1..6 job partials per q-row (online-softmax accumulation) ------
__global__ __launch_bounds__(256) void attn_merge(const __bf16* __restrict__ part,
                                                  const float2* __restrict__ mlb,
                                                  __bf16* __restrict__ att) {
  int flat = blockIdx.x * 256 + threadIdx.x;  // [32 bh][2048 q][8 c8]
  int bh = flat >> 14;
  int rem = flat & 16383;
  int gq = rem >> 3, c8 = rem & 7;
  int qt = gq >> 8, qr = gq & 255;
  int js = JSTART[qt], np = NPARTQ[qt];
  float m = -3.0e38f, wsum = 0.f;
  float o[8];
#pragma unroll
  for (int e = 0; e < 8; ++e) o[e] = 0.f;
  for (int p = 0; p < np; ++p) {
    size_t jidx = (size_t)bh * NJOB + js + p;
    float2 ml = mlb[jidx * 256 + qr];
    float nm = fmaxf(m, ml.x);
    float cold = __expf((m - nm) * 0.03125f);
    float cnew = __expf((ml.x - nm) * 0.03125f) * ml.y;
    m = nm;
    wsum = wsum * cold + cnew;
    bf16x8 v = *(const bf16x8*)(part + (jidx * 256 + qr) * 64 + c8 * 8);
#pragma unroll
    for (int e = 0; e < 8; ++e) o[e] = o[e] * cold + cnew * (float)v[e];
  }
  float inv = 1.0f / wsum;
  bf16x8 ov;
#pragma unroll
  for (int e = 0; e < 8; ++e) ov[e] = (__bf16)(o[e] * inv);
  int b = bh >> 4, hd = bh & 15;
  *(bf16x8*)(att + ((size_t)(b * SEQ + gq)) * DMODEL + hd * HDIM + c8 * 8) = ov;
}

extern "C" void kernel_launch(void* const* d_in, const int* in_sizes, int n_in,
                              void* d_out, int out_size, void* d_ws, size_t ws_size,
                              hipStream_t stream) {
  (void)in_sizes; (void)n_in; (void)out_size;
  const float* x  = (const float*)d_in[0];
  const float* Wq = (const float*)d_in[1];
  const float* bq = (const float*)d_in[2];
  const float* Wk = (const float*)d_in[3];
  const float* bk = (const float*)d_in[4];
  const float* Wv = (const float*)d_in[5];
  const float* bv = (const float*)d_in[6];
  const float* Wo = (const float*)d_in[7];
  const float* bo = (const float*)d_in[8];
  float* out = (float*)d_out;

  const size_t SZ_X = (size_t)BTOK * DMODEL;  // 4M elems
  const size_t SZ_W = (size_t)DMODEL * DMODEL;
  const size_t SZ_H = (size_t)32 * SEQ * HDIM;  // B*H * S * Hd

  char* p = (char*)d_ws;
  __bf16* x_bf  = (__bf16*)p; p += SZ_X * 2;   // reused as vt after gemm<0>
  __bf16* wqkv  = (__bf16*)p; p += 3 * SZ_W * 2;
  __bf16* wo_bf = (__bf16*)p; p += SZ_W * 2;   // contiguous after wqkv (cvt4 relies on it)
  __bf16* q_bf  = (__bf16*)p; p += SZ_H * 2;
  __bf16* k_bf  = (__bf16*)p; p += SZ_H * 2;
  __bf16* v_bf  = (__bf16*)p; p += SZ_H * 2;
  __bf16* at_bf = (__bf16*)p; p += SZ_X * 2;
  if ((size_t)(p - (char*)d_ws) > ws_size) return;
  __bf16* vt_bf = x_bf;  // x dead after gemm<0>

  // job-split partial buffers (mode 1): 27 jobs x 32 bh x 256 q x 64 d
  __bf16* part = (__bf16*)p; p += (size_t)32 * NJOB * 256 * 64 * 2;
  float2* mlb  = (float2*)p; p += (size_t)32 * NJOB * 256 * sizeof(float2);
  const int mode = ((size_t)(p - (char*)d_ws) <= ws_size) ? 1 : 0;

  cvt_f32_bf16<<<(unsigned)(SZ_X / 8 / 256), 256, 0, stream>>>(x, x_bf, (int)(SZ_X / 8));
  cvt4_f32_bf16<<<dim3((unsigned)(SZ_W / 8 / 256), 4), 256, 0, stream>>>(
      Wq, Wk, Wv, Wo, wqkv, (int)(SZ_W / 8));

  gemm_bt<0, 128><<<dim3(32, 24), 256, 0, stream>>>(
      x_bf, wqkv, bq, bk, bv, q_bf, k_bf, v_bf, nullptr);
  transpose_v<<<dim3(SEQ / 64, 32), 256, 0, stream>>>(v_bf, vt_bf);
  attn_fwd<<<dim3(32, mode ? NJOB : 8), 512, 0, stream>>>(q_bf, k_bf, vt_bf, at_bf,
                                                          part, mlb, mode);
  if (mode)
    attn_merge<<<2048, 256, 0, stream>>>(part, mlb, at_bf);
  gemm_bt<1, 64><<<dim3(32, 16), 256, 0, stream>>>(
      at_bf, wo_bf, bo, nullptr, nullptr, nullptr, nullptr, nullptr, out);
}